// Round 1
// 758.535 us; speedup vs baseline: 1.0515x; 1.0515x over previous
//
#include <hip/hip_runtime.h>
#include <math.h>

#define NTOK 16384      // b*n = 8*2048
#define NPB  2048       // tokens per batch
#define DDIM 1024
#define NEXP 64
#define CAP  80
#define ROWF 5120       // NEXP*CAP floats per token row
#define SOUT 83886080LL // NTOK*NEXP*CAP

typedef float vf4 __attribute__((ext_vector_type(4)));

// zero-fill split: k_gate zeros the first K1Z vf4 of out, k_pos zeros the rest.
// total zero region = 2*SOUT floats = 41,943,040 vf4.
#define K1Z_PER_THREAD 192                       // per zero-thread in k_gate
#define K1Z_VF4 (256LL * 256 * K1Z_PER_THREAD)   // 12,582,912 vf4 (201.3 MB)
#define K2Z_BLOCKS 512
#define K2Z_PER_THREAD 224                       // 512*256*224 = 29,360,128 vf4
// 12,582,912 + 29,360,128 = 41,943,040 = 2*SOUT/4  (exact)

// workspace layout (bytes)
#define OFF_ROUTE  0                        // NTOK int (idx1 | idx2<<8 | keep2<<16)
#define OFF_POS1   (OFF_ROUTE + NTOK*4)     // NTOK int
#define OFF_POS2   (OFF_POS1  + NTOK*4)     // NTOK int
#define OFF_CNT1   (OFF_POS2  + NTOK*4)     // 512 int
#define OFF_PART   (OFF_CNT1  + 2048)       // 256*64 float per-block raw-gate sums
#define OFF_G12    (OFF_PART  + 65536)      // NTOK float2

// K1 (R6-proven GEMM core + overlap): waves 0-3 = fused logits GEMM
// (64 tokens x 64 experts per block, 4x4/thread, register-prefetched k-tiles)
// + softmax + top1/top2 + renorm + keep2 + per-block raw-gate sums
// (LDS-BW-bound ~41 us). Waves 4-7 = nontemporal zero-fill of the first
// 201 MB of out, barrier-matched (66 s_barrier each side), hiding the
// zero writes under the compute-bound GEMM (HBM was idle here before).
__global__ __launch_bounds__(512) void k_gate(
    const float* __restrict__ x, const float* __restrict__ w,
    const float* __restrict__ noise,
    int* __restrict__ route, float2* __restrict__ g12,
    float* __restrict__ part, float* __restrict__ out)
{
    __shared__ float xs[32][68];   // xs[k][token]
    __shared__ float wl[32][64];   // wl[k][expert]
    __shared__ float lg[64][68];   // logits
    __shared__ float sG[4][64];

    const int tid = threadIdx.x;

    if (tid >= 256) {
        // ---- zero waves: 256 threads x 192 vf4, contiguous 768KB per block.
        // barrier schedule mirrors the GEMM path exactly: 32 x (A,B) + 2.
        const int zid = tid - 256;
        vf4 zz = {0.f, 0.f, 0.f, 0.f};
        vf4* zbase = (vf4*)out + (size_t)blockIdx.x * (256 * K1Z_PER_THREAD) + zid;
        for (int k0 = 0; k0 < 32; ++k0) {
            __syncthreads();                       // matches post-stage barrier
            #pragma unroll
            for (int m = 0; m < 5; ++m)
                __builtin_nontemporal_store(zz, zbase + (size_t)(k0 * 5 + m) * 256);
            __syncthreads();                       // matches post-FMA barrier
        }
        __syncthreads();                           // matches post-logits barrier
        #pragma unroll
        for (int m = 160; m < 192; ++m)            // overlap the softmax phase
            __builtin_nontemporal_store(zz, zbase + (size_t)m * 256);
        __syncthreads();                           // matches post-sG barrier
        return;
    }

    const int tok0 = blockIdx.x * 64;
    const int tx = tid & 15, ty = tid >> 4;   // expert quad / token quad
    float acc[4][4] = {{0.f}};

    const float* xb = x + (size_t)tok0 * DDIM;
    const int t0 = tid >> 3, c0 = (tid & 7) * 4;   // staging coords

    // preload tile 0 into registers
    float4 px0 = *(const float4*)(xb + (size_t)t0 * DDIM + c0);
    float4 px1 = *(const float4*)(xb + (size_t)(t0 + 32) * DDIM + c0);
    float4 pw0 = ((const float4*)w)[tid];
    float4 pw1 = ((const float4*)w)[tid + 256];

    for (int k0 = 0; k0 < DDIM; k0 += 32) {
        xs[c0+0][t0] = px0.x; xs[c0+1][t0] = px0.y;
        xs[c0+2][t0] = px0.z; xs[c0+3][t0] = px0.w;
        xs[c0+0][t0+32] = px1.x; xs[c0+1][t0+32] = px1.y;
        xs[c0+2][t0+32] = px1.z; xs[c0+3][t0+32] = px1.w;
        ((float4*)wl)[tid]       = pw0;
        ((float4*)wl)[tid + 256] = pw1;
        __syncthreads();

        if (k0 + 32 < DDIM) {   // prefetch next tile while computing this one
            px0 = *(const float4*)(xb + (size_t)t0 * DDIM + k0 + 32 + c0);
            px1 = *(const float4*)(xb + (size_t)(t0 + 32) * DDIM + k0 + 32 + c0);
            const float4* wp = (const float4*)(w + (size_t)(k0 + 32) * NEXP);
            pw0 = wp[tid];
            pw1 = wp[tid + 256];
        }

        #pragma unroll
        for (int k = 0; k < 32; ++k) {
            float4 a  = *(const float4*)&xs[k][ty * 4];
            float4 bb = *(const float4*)&wl[k][tx * 4];
            float av[4] = {a.x, a.y, a.z, a.w};
            float bv[4] = {bb.x, bb.y, bb.z, bb.w};
            #pragma unroll
            for (int i = 0; i < 4; ++i)
                #pragma unroll
                for (int j = 0; j < 4; ++j)
                    acc[i][j] = fmaf(av[i], bv[j], acc[i][j]);
        }
        __syncthreads();
    }

    #pragma unroll
    for (int i = 0; i < 4; ++i)
        *(float4*)&lg[ty * 4 + i][tx * 4] =
            make_float4(acc[i][0], acc[i][1], acc[i][2], acc[i][3]);
    __syncthreads();

    const int lane = tid & 63;
    const int wv   = tid >> 6;
    float gsum_acc = 0.f;

    for (int it = 0; it < 16; ++it) {
        int t = wv * 16 + it;
        float v = lg[t][lane];

        float m = v; int mi = lane;
        #pragma unroll
        for (int off = 32; off; off >>= 1) {
            float ov = __shfl_xor(m, off, 64);
            int   oi = __shfl_xor(mi, off, 64);
            if (ov > m || (ov == m && oi < mi)) { m = ov; mi = oi; }
        }
        float v2 = (lane == mi) ? -INFINITY : v;
        float m2 = v2; int mi2 = lane;
        #pragma unroll
        for (int off = 32; off; off >>= 1) {
            float ov = __shfl_xor(m2, off, 64);
            int   oi = __shfl_xor(mi2, off, 64);
            if (ov > m2 || (ov == m2 && oi < mi2)) { m2 = ov; mi2 = oi; }
        }
        float ex = expf(v - m);
        float s = ex;
        #pragma unroll
        for (int off = 32; off; off >>= 1) s += __shfl_xor(s, off, 64);

        float inv   = 1.0f / s;
        float gate1 = inv;
        float gate2 = expf(m2 - m) * inv;
        gsum_acc += ex * inv;

        float denom = gate1 + gate2 + 1e-9f;
        float g1n = gate1 / denom;
        float g2n = gate2 / denom;

        int gt = tok0 + t;
        if (lane == 0) {
            float u = noise[gt];
            int k2 = (u < (g2n / 0.2f)) ? 1 : 0;
            route[gt] = mi | (mi2 << 8) | (k2 << 16);
            g12[gt] = make_float2(g1n, g2n);
        }
    }

    sG[wv][lane] = gsum_acc;
    __syncthreads();
    if (tid < 64)
        part[blockIdx.x * 64 + tid] =
            sG[0][tid] + sG[1][tid] + sG[2][tid] + sG[3][tid];
}

// K2: blocks 0-7 = 3-phase position scan per batch (unchanged, ~8us of work
// on 8 CUs); blocks 8-519 = nontemporal zero-fill of the remaining 470 MB
// of out (BW-bound, uses the 248 CUs that were idle here before).
__global__ __launch_bounds__(256) void k_pos(
    const int* __restrict__ route,
    int* __restrict__ pos1, int* __restrict__ pos2raw,
    int* __restrict__ cnt1tot, float* __restrict__ out)
{
    const int tid  = threadIdx.x;

    if (blockIdx.x >= 8) {
        const int zb = blockIdx.x - 8;
        vf4 zz = {0.f, 0.f, 0.f, 0.f};
        vf4* base = (vf4*)out + K1Z_VF4
                  + (size_t)zb * (256 * K2Z_PER_THREAD) + tid;
        #pragma unroll 8
        for (int i = 0; i < K2Z_PER_THREAD; ++i)
            __builtin_nontemporal_store(zz, base + (size_t)i * 256);
        return;
    }

    const int b    = blockIdx.x;
    const int lane = tid & 63, wv = tid >> 6;
    __shared__ int sr[NPB];
    __shared__ int h1[32][64], h2[32][64];

    for (int i = tid; i < NPB; i += 256) sr[i] = route[b * NPB + i];
    __syncthreads();

    for (int tau = wv; tau < 32; tau += 4) {
        int c1 = 0, c2 = 0;
        const int* p = &sr[tau * 64];
        #pragma unroll 8
        for (int j = 0; j < 64; ++j) {
            int r = p[j];
            c1 += ((r & 255) == lane);
            c2 += ((r >> 16) && (((r >> 8) & 255) == lane));
        }
        h1[tau][lane] = c1; h2[tau][lane] = c2;
    }
    __syncthreads();

    if (tid < 64) {
        int run = 0;
        #pragma unroll 8
        for (int tau = 0; tau < 32; ++tau) {
            int t = h1[tau][tid]; h1[tau][tid] = run; run += t;
        }
        cnt1tot[b * NEXP + tid] = run;   // pre-capacity top1 total
    } else if (tid < 128) {
        int e = tid - 64, run = 0;
        #pragma unroll 8
        for (int tau = 0; tau < 32; ++tau) {
            int t = h2[tau][e]; h2[tau][e] = run; run += t;
        }
    }
    __syncthreads();

    for (int tau = wv; tau < 32; tau += 4) {
        int c1 = h1[tau][lane], c2 = h2[tau][lane];
        const int* p = &sr[tau * 64];
        const int gbase = b * NPB + tau * 64;
        #pragma unroll 4
        for (int j = 0; j < 64; ++j) {
            int r = p[j];
            if ((r & 255) == lane) pos1[gbase + j] = c1++;
            if ((r >> 16) && (((r >> 8) & 255) == lane)) pos2raw[gbase + j] = c2++;
        }
    }
}

// K3: out is already zeroed by K1/K2 -> only scatter the <=4 nonzero floats
// per token (one token per thread) + the loss block. ~49K scattered 4B
// stores total, ~6us.
__global__ __launch_bounds__(256) void k_out(
    const int* __restrict__ route,
    const int* __restrict__ pos1, const int* __restrict__ pos2raw,
    const int* __restrict__ cnt1tot,
    const float2* __restrict__ g12, const float* __restrict__ part,
    float* __restrict__ out)
{
    const int tid = threadIdx.x;
    const int bid = blockIdx.x;

    if (bid == 64) {
        __shared__ float red[4];
        float v = 0.f;
        for (int p = tid; p < 512; p += 256) {
            int b = p >> 6, e = p & 63;
            float s = 0.f;
            #pragma unroll 8
            for (int c = 0; c < 32; ++c) s += part[((b << 5) + c) * 64 + e];
            v += s * (float)cnt1tot[p];
        }
        #pragma unroll
        for (int off = 32; off; off >>= 1) v += __shfl_xor(v, off, 64);
        if ((tid & 63) == 0) red[tid >> 6] = v;
        __syncthreads();
        if (tid == 0)
            out[2 * SOUT] = (red[0] + red[1] + red[2] + red[3]) * (1.0f / 524288.0f);
        return;
    }

    const int t = bid * 256 + tid;
    const int b = t >> 11;
    const int r  = route[t];
    const int i1 = r & 255, i2 = (r >> 8) & 255, k2 = (r >> 16);
    const float2 g = g12[t];

    float* drow = out + (size_t)t * ROWF;
    float* crow = out + (size_t)SOUT + (size_t)t * ROWF;

    const int p1 = pos1[t];
    if (p1 < CAP) {
        drow[i1 * CAP + p1] = 1.f;
        crow[i1 * CAP + p1] = g.x;
    }
    if (k2) {
        int m1c = min(cnt1tot[(b << 6) + i2], CAP);
        int p2  = pos2raw[t] + m1c;
        if (p2 < CAP) {
            drow[i2 * CAP + p2] = 1.f;
            crow[i2 * CAP + p2] = g.y;
        }
    }
}

extern "C" void kernel_launch(void* const* d_in, const int* in_sizes, int n_in,
                              void* d_out, int out_size, void* d_ws, size_t ws_size,
                              hipStream_t stream) {
    (void)in_sizes; (void)n_in; (void)ws_size; (void)out_size;
    const float* x     = (const float*)d_in[0];
    const float* w     = (const float*)d_in[1];
    const float* noise = (const float*)d_in[2];
    float* out = (float*)d_out;
    char*  ws  = (char*)d_ws;

    int*    route   = (int*)   (ws + OFF_ROUTE);
    int*    pos1    = (int*)   (ws + OFF_POS1);
    int*    pos2raw = (int*)   (ws + OFF_POS2);
    int*    cnt1tot = (int*)   (ws + OFF_CNT1);
    float*  part    = (float*) (ws + OFF_PART);
    float2* g12     = (float2*)(ws + OFF_G12);

    k_gate<<<dim3(NTOK / 64), dim3(512), 0, stream>>>(
        x, w, noise, route, g12, part, out);
    k_pos<<<dim3(8 + K2Z_BLOCKS), dim3(256), 0, stream>>>(
        route, pos1, pos2raw, cnt1tot, out);
    k_out<<<dim3(65), dim3(256), 0, stream>>>(
        route, pos1, pos2raw, cnt1tot, g12, part, out);
}